// Round 1
// baseline (54.266 us; speedup 1.0000x reference)
//
#include <hip/hip_runtime.h>

#define POOL 7
#define NPTS (POOL * POOL)   // 49

// One block per ROI. 256 threads = 4 point-lanes x 64 channel-lanes (float4).
__global__ __launch_bounds__(256) void roialign_kernel(
    const float* __restrict__ p3, const float* __restrict__ p4,
    const float* __restrict__ p5, const float* __restrict__ p6,
    const float* __restrict__ props, float* __restrict__ out,
    int B, int N, int C)
{
    const int roi = blockIdx.x;           // b*N + n
    const int b   = roi / N;

    // ---- per-ROI scalars (redundant per thread, cheap) ----
    const float* pr = props + (size_t)roi * 4;
    const float y1 = pr[0];
    const float x1 = pr[1];
    const float y2 = pr[2];
    const float x2 = pr[3];

    const float h = y2 - y1;
    const float w = x2 - x1;
    // roi_level = log2(sqrt(max(h*w,0)) / (224/1024) + 1e-8)
    const float rl = log2f(sqrtf(fmaxf(h * w, 0.0f)) / 0.21875f + 1e-8f);
    int lvl = 4 + (int)rintf(rl);         // rintf = round half to even, matches jnp.round
    lvl = lvl < 3 ? 3 : (lvl > 6 ? 6 : lvl);

    const float* f;
    int H;
    if      (lvl == 3) { f = p3; H = 128; }
    else if (lvl == 4) { f = p4; H = 64;  }
    else if (lvl == 5) { f = p5; H = 32;  }
    else               { f = p6; H = 16;  }
    const int W = H;
    const float hm1 = (float)(H - 1);
    const float* fb = f + (size_t)b * H * W * C;

    const int tid = threadIdx.x;
    const int pl  = tid >> 6;             // point lane 0..3
    const int cg  = (tid & 63) * 4;       // channel offset (float4 granularity)

    const float dy = y2 - y1;
    const float dx = x2 - x1;

    for (int p0 = 0; p0 < NPTS; p0 += 4) {
        const int p = p0 + pl;
        if (p < NPTS) {
            const int py = p / POOL;
            const int px = p - py * POOL;

            const float ty = (float)py * (1.0f / (POOL - 1));
            const float tx = (float)px * (1.0f / (POOL - 1));

            const float ys = (y1 + ty * dy) * hm1;
            const float xs = (x1 + tx * dx) * hm1;

            const float y0f = floorf(ys);
            const float x0f = floorf(xs);
            const float fy = ys - y0f;
            const float fx = xs - x0f;

            int y0 = (int)y0f;
            y0 = y0 < 0 ? 0 : (y0 > H - 1 ? H - 1 : y0);
            int yi1 = y0 + 1; yi1 = yi1 > H - 1 ? H - 1 : yi1;
            int x0 = (int)x0f;
            x0 = x0 < 0 ? 0 : (x0 > W - 1 ? W - 1 : x0);
            int xi1 = x0 + 1; xi1 = xi1 > W - 1 ? W - 1 : xi1;

            const float4 v00 = *(const float4*)(fb + ((size_t)y0  * W + x0 ) * C + cg);
            const float4 v01 = *(const float4*)(fb + ((size_t)y0  * W + xi1) * C + cg);
            const float4 v10 = *(const float4*)(fb + ((size_t)yi1 * W + x0 ) * C + cg);
            const float4 v11 = *(const float4*)(fb + ((size_t)yi1 * W + xi1) * C + cg);

            float4 o;
            {
                float top, bot;
                top = v00.x + fx * (v01.x - v00.x);
                bot = v10.x + fx * (v11.x - v10.x);
                o.x = top + fy * (bot - top);
                top = v00.y + fx * (v01.y - v00.y);
                bot = v10.y + fx * (v11.y - v10.y);
                o.y = top + fy * (bot - top);
                top = v00.z + fx * (v01.z - v00.z);
                bot = v10.z + fx * (v11.z - v10.z);
                o.z = top + fy * (bot - top);
                top = v00.w + fx * (v01.w - v00.w);
                bot = v10.w + fx * (v11.w - v10.w);
                o.w = top + fy * (bot - top);
            }

            const size_t oidx = (((size_t)roi * NPTS) + p) * C + cg;
            *(float4*)(out + oidx) = o;
        }
    }
}

extern "C" void kernel_launch(void* const* d_in, const int* in_sizes, int n_in,
                              void* d_out, int out_size, void* d_ws, size_t ws_size,
                              hipStream_t stream) {
    (void)d_ws; (void)ws_size; (void)n_in; (void)out_size;

    const float* p3 = (const float*)d_in[0];
    const float* p4 = (const float*)d_in[1];
    const float* p5 = (const float*)d_in[2];
    const float* p6 = (const float*)d_in[3];
    const float* props = (const float*)d_in[4];
    float* out = (float*)d_out;

    const int B = 2;
    const int N = in_sizes[4] / (B * 4);          // 1000
    const int C = in_sizes[0] / (B * 128 * 128);  // 256

    dim3 grid(B * N);
    dim3 block(256);
    roialign_kernel<<<grid, block, 0, stream>>>(p3, p4, p5, p6, props, out, B, N, C);
}

// Round 2
// 49.798 us; speedup vs baseline: 1.0897x; 1.0897x over previous
//
#include <hip/hip_runtime.h>

#define POOL 7
#define NPTS 49

typedef float f4 __attribute__((ext_vector_type(4)));

__device__ __forceinline__ f4 ld4(const float* p) { return *(const f4*)p; }

// One block per ROI. 256 threads = 4 point-lanes x 64 channel-lanes (float4).
// Each thread handles 2 points per macro-iteration -> 8 corner loads in flight.
__global__ __launch_bounds__(256) void roialign_kernel(
    const float* __restrict__ p3, const float* __restrict__ p4,
    const float* __restrict__ p5, const float* __restrict__ p6,
    const float* __restrict__ props, float* __restrict__ out,
    int B, int N, int C)
{
    const int roi = blockIdx.x;           // b*N + n
    const int b   = roi / N;

    const f4 pv = ld4(props + (size_t)roi * 4);
    const float y1 = pv.x, x1 = pv.y, y2 = pv.z, x2 = pv.w;
    const float dy = y2 - y1, dx = x2 - x1;

    // level select: matches jnp.round (rintf = round half to even)
    const float rl = log2f(sqrtf(fmaxf(dy * dx, 0.0f)) / 0.21875f + 1e-8f);
    int lvl = 4 + (int)rintf(rl);
    lvl = lvl < 3 ? 3 : (lvl > 6 ? 6 : lvl);

    const float* f;
    int H;
    if      (lvl == 3) { f = p3; H = 128; }
    else if (lvl == 4) { f = p4; H = 64;  }
    else if (lvl == 5) { f = p5; H = 32;  }
    else               { f = p6; H = 16;  }
    const int W = H;
    const float hm1 = (float)(H - 1);
    const float* fb = f + (size_t)b * H * W * C;

    const int tid = threadIdx.x;
    const int pl  = tid >> 6;             // point lane 0..3
    const int cg  = (tid & 63) << 2;      // channel offset (float4 granularity)

    const int obase = roi * NPTS * C + cg;   // < 2^31

    // per-point corner offsets + weights (int32 offsets keep addressing cheap)
    auto calc = [&](int p, int& o00, int& o01, int& o10, int& o11,
                    float& fx, float& fy) {
        const int py = p / POOL;
        const int px = p - py * POOL;
        const float ys = (y1 + (float)py * (1.0f / (POOL - 1)) * dy) * hm1;
        const float xs = (x1 + (float)px * (1.0f / (POOL - 1)) * dx) * hm1;
        const float y0f = floorf(ys);
        const float x0f = floorf(xs);
        fy = ys - y0f;
        fx = xs - x0f;
        int yA = (int)y0f; yA = yA < 0 ? 0 : (yA > H - 1 ? H - 1 : yA);
        int yB = yA + 1;   yB = yB > H - 1 ? H - 1 : yB;
        int xA = (int)x0f; xA = xA < 0 ? 0 : (xA > W - 1 ? W - 1 : xA);
        int xB = xA + 1;   xB = xB > W - 1 ? W - 1 : xB;
        const int rA = yA * W, rB = yB * W;
        o00 = (rA + xA) * C + cg;
        o01 = (rA + xB) * C + cg;
        o10 = (rB + xA) * C + cg;
        o11 = (rB + xB) * C + cg;
    };

    #pragma unroll
    for (int p0 = 0; p0 < 48; p0 += 8) {
        const int pa = p0 + pl;   // <= 43
        const int pb = pa + 4;    // <= 47
        int a00, a01, a10, a11, b00, b01, b10, b11;
        float afx, afy, bfx, bfy;
        calc(pa, a00, a01, a10, a11, afx, afy);
        calc(pb, b00, b01, b10, b11, bfx, bfy);

        const f4 va00 = ld4(fb + a00), va01 = ld4(fb + a01);
        const f4 va10 = ld4(fb + a10), va11 = ld4(fb + a11);
        const f4 vb00 = ld4(fb + b00), vb01 = ld4(fb + b01);
        const f4 vb10 = ld4(fb + b10), vb11 = ld4(fb + b11);

        const f4 ta = va00 + afx * (va01 - va00);
        const f4 ba = va10 + afx * (va11 - va10);
        const f4 oa = ta + afy * (ba - ta);
        const f4 tb = vb00 + bfx * (vb01 - vb00);
        const f4 bb = vb10 + bfx * (vb11 - vb10);
        const f4 ob = tb + bfy * (bb - tb);

        __builtin_nontemporal_store(oa, (f4*)(out + obase + pa * C));
        __builtin_nontemporal_store(ob, (f4*)(out + obase + pb * C));
    }

    // tail: point 48 (only point-lane 0)
    if (pl == 0) {
        int o00, o01, o10, o11;
        float fx, fy;
        calc(48, o00, o01, o10, o11, fx, fy);
        const f4 v00 = ld4(fb + o00), v01 = ld4(fb + o01);
        const f4 v10 = ld4(fb + o10), v11 = ld4(fb + o11);
        const f4 t  = v00 + fx * (v01 - v00);
        const f4 bo = v10 + fx * (v11 - v10);
        const f4 o  = t + fy * (bo - t);
        __builtin_nontemporal_store(o, (f4*)(out + obase + 48 * C));
    }
}

extern "C" void kernel_launch(void* const* d_in, const int* in_sizes, int n_in,
                              void* d_out, int out_size, void* d_ws, size_t ws_size,
                              hipStream_t stream) {
    (void)d_ws; (void)ws_size; (void)n_in; (void)out_size;

    const float* p3 = (const float*)d_in[0];
    const float* p4 = (const float*)d_in[1];
    const float* p5 = (const float*)d_in[2];
    const float* p6 = (const float*)d_in[3];
    const float* props = (const float*)d_in[4];
    float* out = (float*)d_out;

    const int B = 2;
    const int N = in_sizes[4] / (B * 4);          // 1000
    const int C = in_sizes[0] / (B * 128 * 128);  // 256

    dim3 grid(B * N);
    dim3 block(256);
    roialign_kernel<<<grid, block, 0, stream>>>(p3, p4, p5, p6, props, out, B, N, C);
}

// Round 3
// 32.893 us; speedup vs baseline: 1.6498x; 1.5139x over previous
//
#include <hip/hip_runtime.h>

#define POOL 7
#define NPTS 49

typedef float f4 __attribute__((ext_vector_type(4)));

__device__ __forceinline__ f4 ld4(const float* p) { return *(const f4*)p; }

__device__ __forceinline__ int roi_level(float dy, float dx) {
    // matches jnp: log2(sqrt(max(h*w,0)) / 0.21875 + 1e-8), round half-even
    const float rl = log2f(sqrtf(fmaxf(dy * dx, 0.0f)) / 0.21875f + 1e-8f);
    int lvl = 4 + (int)rintf(rl);
    return lvl < 3 ? 3 : (lvl > 6 ? 6 : lvl);
}

__device__ __forceinline__ int bucket_key(const float* props, int r, int N) {
    const f4 p = ld4(props + (size_t)r * 4);
    const int lvl = roi_level(p.z - p.x, p.w - p.y);
    const float yc = 0.5f * (p.x + p.z);
    int oct = (int)(yc * 8.0f);
    oct = oct < 0 ? 0 : (oct > 7 ? 7 : oct);
    int lg = lvl - 3; lg = lg < 0 ? 0 : (lg > 1 ? 1 : lg);  // data only hits {3,4}
    const int b = r >= N ? 1 : 0;
    return ((b << 1) | lg) * 8 + oct;   // [0,32)
}

// Single-block counting sort: order[] gets ROI indices grouped by
// (batch, level, y-octant) -> spatially/level coherent chunks.
__global__ __launch_bounds__(1024) void bucket_kernel(
    const float* __restrict__ props, int* __restrict__ order, int BN, int N)
{
    __shared__ int hist[32];
    __shared__ int offs[32];
    const int tid = threadIdx.x;
    if (tid < 32) hist[tid] = 0;
    __syncthreads();
    for (int r = tid; r < BN; r += 1024)
        atomicAdd(&hist[bucket_key(props, r, N)], 1);
    __syncthreads();
    if (tid == 0) {
        int acc = 0;
        for (int i = 0; i < 32; ++i) { offs[i] = acc; acc += hist[i]; }
    }
    __syncthreads();
    for (int r = tid; r < BN; r += 1024) {
        const int k = bucket_key(props, r, N);
        const int pos = atomicAdd(&offs[k], 1);
        order[pos] = r;
    }
}

// One block per ROI slot. 256 threads = 4 point-lanes x 64 channel-lanes.
__global__ __launch_bounds__(256) void roialign_kernel(
    const float* __restrict__ p3, const float* __restrict__ p4,
    const float* __restrict__ p5, const float* __restrict__ p6,
    const float* __restrict__ props, const int* __restrict__ order,
    float* __restrict__ out, int B, int N, int C, int nwg)
{
    // bijective chunked XCD swizzle (m204): XCD k gets a contiguous run of
    // sorted slots -> per-XCD working set is one (batch,level,y-band) window.
    const int s   = blockIdx.x;
    const int q   = nwg >> 3, rr = nwg & 7;
    const int xcd = s & 7, idx = s >> 3;
    const int s2  = (xcd < rr ? xcd * (q + 1) : rr * (q + 1) + (xcd - rr) * q) + idx;
    const int roi = order[s2];
    const int b   = roi >= N ? 1 : 0;

    const f4 pv = ld4(props + (size_t)roi * 4);
    const float y1 = pv.x, x1 = pv.y, y2 = pv.z, x2 = pv.w;
    const float dy = y2 - y1, dx = x2 - x1;

    const int lvl = roi_level(dy, dx);
    const float* f;
    int H;
    if      (lvl == 3) { f = p3; H = 128; }
    else if (lvl == 4) { f = p4; H = 64;  }
    else if (lvl == 5) { f = p5; H = 32;  }
    else               { f = p6; H = 16;  }
    const int W = H;
    const float hm1 = (float)(H - 1);
    const float* fb = f + (size_t)b * H * W * C;

    const int tid = threadIdx.x;
    const int pl  = tid >> 6;             // point lane 0..3
    const int cg  = (tid & 63) << 2;      // channel offset (float4)

    const int obase = roi * NPTS * C + cg;

    auto calc = [&](int p, int& o00, int& o01, int& o10, int& o11,
                    float& fx, float& fy) {
        const int py = p / POOL;
        const int px = p - py * POOL;
        const float ys = (y1 + (float)py * (1.0f / (POOL - 1)) * dy) * hm1;
        const float xs = (x1 + (float)px * (1.0f / (POOL - 1)) * dx) * hm1;
        const float y0f = floorf(ys);
        const float x0f = floorf(xs);
        fy = ys - y0f;
        fx = xs - x0f;
        int yA = (int)y0f; yA = yA < 0 ? 0 : (yA > H - 1 ? H - 1 : yA);
        int yB = yA + 1;   yB = yB > H - 1 ? H - 1 : yB;
        int xA = (int)x0f; xA = xA < 0 ? 0 : (xA > W - 1 ? W - 1 : xA);
        int xB = xA + 1;   xB = xB > W - 1 ? W - 1 : xB;
        const int rA = yA * W, rB = yB * W;
        o00 = (rA + xA) * C + cg;
        o01 = (rA + xB) * C + cg;
        o10 = (rB + xA) * C + cg;
        o11 = (rB + xB) * C + cg;
    };

    #pragma unroll
    for (int p0 = 0; p0 < 48; p0 += 8) {
        const int pa = p0 + pl;   // <= 43
        const int pb = pa + 4;    // <= 47
        int a00, a01, a10, a11, b00, b01, b10, b11;
        float afx, afy, bfx, bfy;
        calc(pa, a00, a01, a10, a11, afx, afy);
        calc(pb, b00, b01, b10, b11, bfx, bfy);

        const f4 va00 = ld4(fb + a00), va01 = ld4(fb + a01);
        const f4 va10 = ld4(fb + a10), va11 = ld4(fb + a11);
        const f4 vb00 = ld4(fb + b00), vb01 = ld4(fb + b01);
        const f4 vb10 = ld4(fb + b10), vb11 = ld4(fb + b11);

        const f4 ta = va00 + afx * (va01 - va00);
        const f4 ba = va10 + afx * (va11 - va10);
        const f4 oa = ta + afy * (ba - ta);
        const f4 tb = vb00 + bfx * (vb01 - vb00);
        const f4 bb = vb10 + bfx * (vb11 - vb10);
        const f4 ob = tb + bfy * (bb - tb);

        __builtin_nontemporal_store(oa, (f4*)(out + obase + pa * C));
        __builtin_nontemporal_store(ob, (f4*)(out + obase + pb * C));
    }

    if (pl == 0) {  // tail: point 48
        int o00, o01, o10, o11;
        float fx, fy;
        calc(48, o00, o01, o10, o11, fx, fy);
        const f4 v00 = ld4(fb + o00), v01 = ld4(fb + o01);
        const f4 v10 = ld4(fb + o10), v11 = ld4(fb + o11);
        const f4 t  = v00 + fx * (v01 - v00);
        const f4 bo = v10 + fx * (v11 - v10);
        const f4 o  = t + fy * (bo - t);
        __builtin_nontemporal_store(o, (f4*)(out + obase + 48 * C));
    }
}

extern "C" void kernel_launch(void* const* d_in, const int* in_sizes, int n_in,
                              void* d_out, int out_size, void* d_ws, size_t ws_size,
                              hipStream_t stream) {
    (void)ws_size; (void)n_in; (void)out_size;

    const float* p3 = (const float*)d_in[0];
    const float* p4 = (const float*)d_in[1];
    const float* p5 = (const float*)d_in[2];
    const float* p6 = (const float*)d_in[3];
    const float* props = (const float*)d_in[4];
    float* out = (float*)d_out;
    int* order = (int*)d_ws;

    const int B = 2;
    const int N = in_sizes[4] / (B * 4);          // 1000
    const int C = in_sizes[0] / (B * 128 * 128);  // 256
    const int BN = B * N;

    bucket_kernel<<<1, 1024, 0, stream>>>(props, order, BN, N);
    roialign_kernel<<<BN, 256, 0, stream>>>(p3, p4, p5, p6, props, order,
                                            out, B, N, C, BN);
}